// Round 4
// baseline (623.302 us; speedup 1.0000x reference)
//
#include <hip/hip_runtime.h>

// ===== DIAGNOSTIC ROUND =====
// Three structurally different kernels all measure 210-220us (3.2 TB/s eff)
// against a ~107us HBM roofline, and our dispatch never appears in the top-5
// rocprof table (harness fill kernels are ~400us). This round: persistent
// blocks + REPS=3 internal repeat (each rep HBM-cold, L3 fully cycled between
// visits) so our dispatch becomes the longest and we get real counters.
// Output is written REPS times with identical values -> deterministic.

constexpr int POS = 63;
constexpr int LAT = 256;
constexpr int DIM = POS + LAT;   // 319
constexpr int NCH = 192;         // 3 * 64 clusters
constexpr int SLOTS = 81;        // float4 slots per (d, ch) table row
constexpr int RPB = 16;          // rows per block-group
constexpr int LDS_SLOTS = RPB * DIM / 4;  // 1276 float4 = 20416 B -> 8 blocks/CU
constexpr size_t WTAB_BYTES = (size_t)4 * NCH * SLOTS * 16;  // 995,328 B
constexpr int GRID = 2048;       // 8 persistent blocks per CU
constexpr int REPS = 3;          // diagnostic repeat factor

// ---------- init: shifted weight tables in workspace ----------
// ws4[(d*NCH + ch)*SLOTS + sl][c] = w_cat(ch, 4*sl + c - d), 0 outside [0,319)
__global__ __launch_bounds__(256) void build_wtab(
    const float* __restrict__ Wp,   // [192, 63]
    const float* __restrict__ Wf,   // [192, 256]
    float4* __restrict__ ws4)
{
    const int idx = blockIdx.x * 256 + threadIdx.x;
    const int total = 4 * NCH * SLOTS;   // 62208
    if (idx >= total) return;
    const int sl = idx % SLOTS;
    const int t  = idx / SLOTS;
    const int ch = t % NCH;
    const int d  = t / NCH;
    float v[4];
#pragma unroll
    for (int c = 0; c < 4; ++c) {
        const int k = 4 * sl + c - d;
        float w = 0.f;
        if (k >= 0 && k < POS)            w = Wp[ch * POS + k];
        else if (k >= POS && k < DIM)     w = Wf[ch * LAT + (k - POS)];
        v[c] = w;
    }
    ws4[idx] = make_float4(v[0], v[1], v[2], v[3]);
}

// ---------- DPP wave64 sum (pure VALU), result valid in lane 63 ----------
template <int CTRL>
__device__ __forceinline__ float dpp_add_step(float x) {
    int s = __builtin_amdgcn_update_dpp(0, __float_as_int(x), CTRL,
                                        0xF, 0xF, /*bound_ctrl=*/true);
    return x + __int_as_float(s);
}
__device__ __forceinline__ float wave_reduce_sum(float x) {
    x = dpp_add_step<0x111>(x);  // row_shr:1
    x = dpp_add_step<0x112>(x);  // row_shr:2
    x = dpp_add_step<0x114>(x);  // row_shr:4
    x = dpp_add_step<0x118>(x);  // row_shr:8
    x = dpp_add_step<0x142>(x);  // row_bcast15
    x = dpp_add_step<0x143>(x);  // row_bcast31
    return x;
}

// ---------- persistent main kernel ----------
__global__ __launch_bounds__(256) void lad_persist(
    const float* __restrict__ X,
    const int*   __restrict__ cid,
    const float4* __restrict__ ws4,
    float*       __restrict__ out,
    int n)
{
    __shared__ float4 xs[LDS_SLOTS];

    const int ngroups = (n + RPB - 1) / RPB;   // 32768 (n divisible by 16)
    const int t = threadIdx.x;
    const int w = t >> 6;
    const int l = t & 63;

    for (int rep = 0; rep < REPS; ++rep) {
        for (int g = blockIdx.x; g < ngroups; g += GRID) {
            const int r0 = g * RPB;

            __syncthreads();   // previous group's LDS reads complete

            // Stage 16 rows (5104 floats, 16B-aligned) linearly into LDS.
#pragma unroll
            for (int i = 0; i < 5; ++i) {
                const int slot = i * 256 + t;
                if (slot < LDS_SLOTS) {
                    const char* gp = (const char*)X
                        + (size_t)r0 * DIM * 4 + (size_t)slot * 16;
                    __builtin_amdgcn_global_load_lds(
                        (const __attribute__((address_space(1))) unsigned int*)gp,
                        (__attribute__((address_space(3))) unsigned int*)&xs[slot],
                        16, 0, 0);
                }
            }
            __syncthreads();

            // Each wave computes 4 consecutive rows.
#pragma unroll
            for (int q = 0; q < 4; ++q) {
                const int ri = w * 4 + q;
                const int r  = r0 + ri;
                if (r >= n) break;

                const int off = ri * DIM;
                const int d   = off & 3;
                const int s0  = off >> 2;
                const int p2n = d ? 17 : 16;

                const int c3 = 3 * cid[r];
                const float4* wt = ws4 + (size_t)(d * NCH + c3) * SLOTS;

                const float4 xa = xs[s0 + l];
                const bool m2 = (l < p2n);
                float4 xb;
                if (m2) xb = xs[s0 + 64 + l];

                float acc[3];
#pragma unroll
                for (int j = 0; j < 3; ++j) {
                    const float4* wr = wt + (size_t)j * SLOTS;
                    const float4 wa = wr[l];
                    float a = xa.x * wa.x + xa.y * wa.y
                            + xa.z * wa.z + xa.w * wa.w;
                    if (m2) {
                        const float4 wb = wr[64 + l];
                        a += xb.x * wb.x + xb.y * wb.y
                           + xb.z * wb.z + xb.w * wb.w;
                    }
                    acc[j] = wave_reduce_sum(a);
                }
                if (l == 63) {
                    float* o = out + (size_t)r * 3;
                    o[0] = acc[0];
                    o[1] = acc[1];
                    o[2] = acc[2];
                }
            }
        }
    }
}

// ---------- fallback if workspace too small (not expected) ----------
__global__ __launch_bounds__(256) void lad_fallback(
    const float* __restrict__ X,
    const int*   __restrict__ cid,
    const float* __restrict__ Wp,
    const float* __restrict__ Wf,
    float*       __restrict__ out,
    int n)
{
    const int lane = threadIdx.x & 63;
    const int wave = (int)((blockIdx.x * blockDim.x + threadIdx.x) >> 6);
    if (wave >= n) return;
    const size_t row = (size_t)wave;
    const float* xrow = X + row * (size_t)DIM;
    const float* xf   = xrow + POS;
    const int c3 = cid[row] * 3;
    const float* wp0 = Wp + (size_t)c3 * POS;
    const float* wf0 = Wf + (size_t)c3 * LAT;
    float a0 = 0.f, a1 = 0.f, a2 = 0.f;
#pragma unroll
    for (int i = 0; i < 4; ++i) {
        const int k = lane + 64 * i;
        const float x = xf[k];
        a0 = fmaf(x, wf0[k], a0);
        a1 = fmaf(x, wf0[k + LAT], a1);
        a2 = fmaf(x, wf0[k + 2 * LAT], a2);
    }
    if (lane < POS) {
        const float x = xrow[lane];
        a0 = fmaf(x, wp0[lane], a0);
        a1 = fmaf(x, wp0[lane + POS], a1);
        a2 = fmaf(x, wp0[lane + 2 * POS], a2);
    }
    a0 = wave_reduce_sum(a0);
    a1 = wave_reduce_sum(a1);
    a2 = wave_reduce_sum(a2);
    if (lane == 63) {
        float* o = out + row * 3;
        o[0] = a0; o[1] = a1; o[2] = a2;
    }
}

extern "C" void kernel_launch(void* const* d_in, const int* in_sizes, int n_in,
                              void* d_out, int out_size, void* d_ws, size_t ws_size,
                              hipStream_t stream) {
    const float* X   = (const float*)d_in[0];
    const int*   cid = (const int*)d_in[1];
    const float* Wp  = (const float*)d_in[2];
    const float* Wf  = (const float*)d_in[3];
    float* out = (float*)d_out;
    const int n = in_sizes[1];

    if (ws_size >= WTAB_BYTES) {
        float4* ws4 = (float4*)d_ws;
        build_wtab<<<243, 256, 0, stream>>>(Wp, Wf, ws4);
        lad_persist<<<GRID, 256, 0, stream>>>(X, cid, ws4, out, n);
    } else {
        const int blocks = (n + 3) / 4;
        lad_fallback<<<blocks, 256, 0, stream>>>(X, cid, Wp, Wf, out, n);
    }
}

// Round 5
// 173.077 us; speedup vs baseline: 3.6013x; 3.6013x over previous
//
#include <hip/hip_runtime.h>

// LinearAutoDecoder, cluster-binned.
// Theory: R1-R3 (all ~210-220us) were limited by the CU vector-memory path:
// each row re-read its cluster's 3.9 KB of weights (2.04 GB total, L2-resident,
// invisible in FETCH_SIZE). Binning rows by cluster lets a wave keep the
// weights in 15 VGPRs across a 64-row run, cutting vector-path bytes ~4x.
// Output determinism: each row's result depends only on X[row], cid[row], W;
// perm order (atomic scatter) does not affect written values.

constexpr int POS = 63;
constexpr int LAT = 256;
constexpr int DIM = POS + LAT;   // 319
constexpr int NCLUST = 64;
constexpr int WPAD = 320;        // padded weight row (5*64); wcat[ch][319] = 0
constexpr int HB = 256;          // histogram/scatter blocks

// ws layout: float wcat[192*320] | int hist[64] | int off[64] | int perm[n]
constexpr size_t WCAT_ELEMS = (size_t)192 * WPAD;          // 61440 floats
constexpr size_t HIST_OFF = WCAT_ELEMS * 4;                // bytes
constexpr size_t OFF_OFF  = HIST_OFF + 64 * 4;
constexpr size_t PERM_OFF = OFF_OFF + 64 * 4;
static size_t ws_needed(int n) { return PERM_OFF + (size_t)n * 4; }

// ---------- init: padded concatenated weights + zero histogram ----------
__global__ __launch_bounds__(256) void init_wcat(
    const float* __restrict__ Wp,   // [192, 63]
    const float* __restrict__ Wf,   // [192, 256]
    float* __restrict__ wcat, int* __restrict__ hist)
{
    const int idx = blockIdx.x * 256 + threadIdx.x;
    if (idx < NCLUST) hist[idx] = 0;
    if (idx >= (int)WCAT_ELEMS) return;
    const int ch = idx / WPAD, k = idx % WPAD;
    float w = 0.f;
    if (k < POS)            w = Wp[ch * POS + k];
    else if (k < DIM)       w = Wf[ch * LAT + (k - POS)];
    wcat[idx] = w;
}

// ---------- histogram ----------
__global__ __launch_bounds__(256) void hist_kernel(
    const int* __restrict__ cid, int n, int* __restrict__ hist)
{
    __shared__ int h[NCLUST];
    const int t = threadIdx.x;
    if (t < NCLUST) h[t] = 0;
    __syncthreads();
    const int chunk = (n + HB - 1) / HB;
    const int lo = blockIdx.x * chunk;
    const int hi = min(lo + chunk, n);
    for (int i = lo + t; i < hi; i += 256)
        atomicAdd(&h[cid[i]], 1);
    __syncthreads();
    if (t < NCLUST) atomicAdd(&hist[t], h[t]);
}

// ---------- exclusive scan (64 bins, trivial) ----------
__global__ void scan_kernel(const int* __restrict__ hist, int* __restrict__ off)
{
    if (threadIdx.x == 0 && blockIdx.x == 0) {
        int acc = 0;
        for (int c = 0; c < NCLUST; ++c) { off[c] = acc; acc += hist[c]; }
    }
}

// ---------- scatter row indices into cluster-sorted perm ----------
__global__ __launch_bounds__(256) void scatter_kernel(
    const int* __restrict__ cid, int n, int* __restrict__ off,
    int* __restrict__ perm)
{
    __shared__ int h[NCLUST];
    const int t = threadIdx.x;
    if (t < NCLUST) h[t] = 0;
    __syncthreads();
    const int chunk = (n + HB - 1) / HB;
    const int lo = blockIdx.x * chunk;
    const int hi = min(lo + chunk, n);
    for (int i = lo + t; i < hi; i += 256)
        atomicAdd(&h[cid[i]], 1);
    __syncthreads();
    if (t < NCLUST) h[t] = atomicAdd(&off[t], h[t]);  // reserve global range
    __syncthreads();
    for (int i = lo + t; i < hi; i += 256) {
        const int c = cid[i];
        const int p = atomicAdd(&h[c], 1);            // cursor within range
        perm[p] = i;
    }
}

// ---------- DPP wave64 sum (pure VALU), result valid in lane 63 ----------
template <int CTRL>
__device__ __forceinline__ float dpp_add_step(float x) {
    int s = __builtin_amdgcn_update_dpp(0, __float_as_int(x), CTRL,
                                        0xF, 0xF, /*bound_ctrl=*/true);
    return x + __int_as_float(s);
}
__device__ __forceinline__ float wave_reduce_sum(float x) {
    x = dpp_add_step<0x111>(x);  // row_shr:1
    x = dpp_add_step<0x112>(x);  // row_shr:2
    x = dpp_add_step<0x114>(x);  // row_shr:4
    x = dpp_add_step<0x118>(x);  // row_shr:8
    x = dpp_add_step<0x142>(x);  // row_bcast15
    x = dpp_add_step<0x143>(x);  // row_bcast31
    return x;
}

// ---------- main compute: one wave per 64 perm entries ----------
__global__ __launch_bounds__(256) void lad_binned(
    const float* __restrict__ X,
    const int*   __restrict__ cid,
    const int*   __restrict__ perm,
    const float* __restrict__ wcat,
    float*       __restrict__ out,
    int n)
{
    const int l   = threadIdx.x & 63;
    const int wid = (int)((blockIdx.x * blockDim.x + threadIdx.x) >> 6);
    const int base = wid * 64;
    if (base >= n) return;

    // Prefetch this wave's 64 perm entries + their clusters (2 coalesced/gathered loads).
    int vperm = 0, vcid = 0;
    if (base + l < n) { vperm = perm[base + l]; vcid = cid[vperm]; }

    int cur = -1;
    float w0[5], w1[5], w2[5];

    const int cnt = min(64, n - base);
    for (int j = 0; j < cnt; ++j) {
        const int r = __builtin_amdgcn_readlane(vperm, j);   // uniform row idx
        const int c = __builtin_amdgcn_readlane(vcid, j);    // uniform cluster
        if (c != cur) {            // rare: ~once per wave (sorted order)
            cur = c;
            const float* wb = wcat + (size_t)(3 * c) * WPAD + l;
#pragma unroll
            for (int i = 0; i < 5; ++i) {
                w0[i] = wb[i * 64];
                w1[i] = wb[WPAD + i * 64];
                w2[i] = wb[2 * WPAD + i * 64];
            }
        }
        const float* xr = X + (size_t)r * DIM + l;
        float a0 = 0.f, a1 = 0.f, a2 = 0.f;
#pragma unroll
        for (int i = 0; i < 4; ++i) {
            const float x = xr[i * 64];
            a0 = fmaf(x, w0[i], a0);
            a1 = fmaf(x, w1[i], a1);
            a2 = fmaf(x, w2[i], a2);
        }
        {   // tail features 256..318: lane 63 masked (w*[4] at k=319 is 0 anyway)
            const float x = (l < 63) ? xr[256] : 0.f;
            a0 = fmaf(x, w0[4], a0);
            a1 = fmaf(x, w1[4], a1);
            a2 = fmaf(x, w2[4], a2);
        }
        a0 = wave_reduce_sum(a0);
        a1 = wave_reduce_sum(a1);
        a2 = wave_reduce_sum(a2);
        if (l == 63) {
            float* o = out + (size_t)r * 3;
            o[0] = a0; o[1] = a1; o[2] = a2;
        }
    }
}

// ---------- fallback (R2 kernel) if workspace too small ----------
__global__ __launch_bounds__(256) void lad_fallback(
    const float* __restrict__ X,
    const int*   __restrict__ cid,
    const float* __restrict__ Wp,
    const float* __restrict__ Wf,
    float*       __restrict__ out,
    int n)
{
    const int lane = threadIdx.x & 63;
    const int wave = (int)((blockIdx.x * blockDim.x + threadIdx.x) >> 6);
    if (wave >= n) return;
    const size_t row = (size_t)wave;
    const float* xrow = X + row * (size_t)DIM;
    const float* xf   = xrow + POS;
    const int c3 = cid[row] * 3;
    const float* wp0 = Wp + (size_t)c3 * POS;
    const float* wf0 = Wf + (size_t)c3 * LAT;
    float a0 = 0.f, a1 = 0.f, a2 = 0.f;
#pragma unroll
    for (int i = 0; i < 4; ++i) {
        const int k = lane + 64 * i;
        const float x = xf[k];
        a0 = fmaf(x, wf0[k], a0);
        a1 = fmaf(x, wf0[k + LAT], a1);
        a2 = fmaf(x, wf0[k + 2 * LAT], a2);
    }
    if (lane < POS) {
        const float x = xrow[lane];
        a0 = fmaf(x, wp0[lane], a0);
        a1 = fmaf(x, wp0[lane + POS], a1);
        a2 = fmaf(x, wp0[lane + 2 * POS], a2);
    }
    a0 = wave_reduce_sum(a0);
    a1 = wave_reduce_sum(a1);
    a2 = wave_reduce_sum(a2);
    if (lane == 63) {
        float* o = out + row * 3;
        o[0] = a0; o[1] = a1; o[2] = a2;
    }
}

extern "C" void kernel_launch(void* const* d_in, const int* in_sizes, int n_in,
                              void* d_out, int out_size, void* d_ws, size_t ws_size,
                              hipStream_t stream) {
    const float* X   = (const float*)d_in[0];
    const int*   cid = (const int*)d_in[1];
    const float* Wp  = (const float*)d_in[2];
    const float* Wf  = (const float*)d_in[3];
    float* out = (float*)d_out;
    const int n = in_sizes[1];

    if (ws_size >= ws_needed(n)) {
        char* ws = (char*)d_ws;
        float* wcat = (float*)ws;
        int*   hist = (int*)(ws + HIST_OFF);
        int*   off  = (int*)(ws + OFF_OFF);
        int*   perm = (int*)(ws + PERM_OFF);

        const int init_blocks = ((int)WCAT_ELEMS + 255) / 256;  // 240
        init_wcat<<<init_blocks, 256, 0, stream>>>(Wp, Wf, wcat, hist);
        hist_kernel<<<HB, 256, 0, stream>>>(cid, n, hist);
        scan_kernel<<<1, 64, 0, stream>>>(hist, off);
        scatter_kernel<<<HB, 256, 0, stream>>>(cid, n, off, perm);

        const int waves = (n + 63) / 64;
        const int blocks = (waves + 3) / 4;
        lad_binned<<<blocks, 256, 0, stream>>>(X, cid, perm, wcat, out, n);
    } else {
        const int blocks = (n + 3) / 4;
        lad_fallback<<<blocks, 256, 0, stream>>>(X, cid, Wp, Wf, out, n);
    }
}